// Round 5
// baseline (216.680 us; speedup 1.0000x reference)
//
#include <hip/hip_runtime.h>
#include <math.h>

// KabschLoss: loss = mean( (xc @ R - yc)^2 ), R = U Vh from SVD of C = xc^T yc.
// Identity: sum |xc R - yc|^2 = Sx + Sy - 2*nuclear_norm(C). Only per-batch raw
// moments + singular values of the 3x3 covariance needed.
//
// R4: R3 was stalled 70%+ (libm eigen ~500 instr/tile, ds_swizzle butterfly on
// the LDS pipe, only 16% occupancy). Fixes: (1) fast eigen (A&S acos poly +
// v_cos in revolutions + v_rcp/v_sqrt; error ~1e-4 vs 3.5e-2 threshold),
// (2) DPP butterfly on the VALU pipe (quad_perm/half_mirror/mirror/bcast15,
// row_mask 0xA keeps batches separate; valid sums in lanes 16-31/48-63,
// extracted via readlane at the end), (3) 8192 waves (12/CU, 3 blocks/CU).
// Per-wave DMA double-buffer from R3 kept (global_load_lds, no VGPR cost).

#define NPTS 128
#define WPB 4
#define BLOCKS 2048
#define TOTAL_WAVES (BLOCKS * WPB)   // 8192
#define TILE_F4 192                  // float4 per array per 2-batch tile
#define BUF_F4 (2 * TILE_F4)         // x + y = 6 KB

__device__ __forceinline__ void stage_tile(const float4* __restrict__ x4,
                                           const float4* __restrict__ y4,
                                           size_t tile, float4* buf, int lane) {
    const size_t base = tile * TILE_F4;
    #pragma unroll
    for (int r = 0; r < 3; ++r) {
        __builtin_amdgcn_global_load_lds(
            (const __attribute__((address_space(1))) void*)(x4 + base + r * 64 + lane),
            (__attribute__((address_space(3))) void*)(buf + r * 64), 16, 0, 0);
        __builtin_amdgcn_global_load_lds(
            (const __attribute__((address_space(1))) void*)(y4 + base + r * 64 + lane),
            (__attribute__((address_space(3))) void*)(buf + TILE_F4 + r * 64), 16, 0, 0);
    }
}

template<int CTRL, int RMASK>
__device__ __forceinline__ float dpp_add(float v) {
    int t = __builtin_amdgcn_update_dpp(0, __builtin_bit_cast(int, v),
                                        CTRL, RMASK, 0xF, true);
    return v + __builtin_bit_cast(float, t);
}

__device__ __forceinline__ float acos_fast(float x) {
    // Abramowitz-Stegun 4.4.45: |err| <= 6.8e-5 rad on [0,1].
    float ax = fabsf(x);
    float p = fmaf(ax, -0.0187293f, 0.0742610f);
    p = fmaf(ax, p, -0.2121144f);
    p = fmaf(ax, p, 1.5707288f);
    float s = __builtin_amdgcn_sqrtf(fmaxf(1.0f - ax, 0.0f));
    float r = s * p;
    return (x < 0.0f) ? (3.14159265358979f - r) : r;
}

__global__ __launch_bounds__(256, 3) void kabsch_kernel(
        const float4* __restrict__ x4, const float4* __restrict__ y4,
        float* __restrict__ out, float scale, int tilesPerWave) {
    __shared__ float4 smem[WPB][2][BUF_F4];   // 48 KB
    __shared__ float wsum[WPB];

    const int tid  = threadIdx.x;
    const int lane = tid & 63;
    const int wave = tid >> 6;
    const int w    = blockIdx.x * WPB + wave;

    float4* buf0 = &smem[wave][0][0];
    float4* buf1 = &smem[wave][1][0];

    stage_tile(x4, y4, (size_t)w, buf0, lane);   // prologue: tile 0

    const int g   = lane >> 5;    // batch within tile
    const int sub = lane & 31;    // 4 points per lane (12 floats, phase 0)
    const float invN = 1.0f / (float)NPTS;

    float wave_acc = 0.f;

    for (int t = 0; t < tilesPerWave; ++t) {
        float4* cur = (t & 1) ? buf1 : buf0;
        float4* nxt = (t & 1) ? buf0 : buf1;

        // Drain this wave's 6 outstanding DMA loads (per-wave, no barrier).
        asm volatile("s_waitcnt vmcnt(0)" ::: "memory");

        const float4* xs = cur + g * 96 + sub * 3;
        const float4* ys = cur + TILE_F4 + g * 96 + sub * 3;
        float4 xv0 = xs[0], xv1 = xs[1], xv2 = xs[2];
        float4 yv0 = ys[0], yv1 = ys[1], yv2 = ys[2];

        // Prefetch tile t+1 while computing tile t.
        if (t + 1 < tilesPerWave)
            stage_tile(x4, y4, (size_t)w + (size_t)(t + 1) * TOTAL_WAVES, nxt, lane);

        float fx[12], fy[12];
        fx[0]=xv0.x; fx[1]=xv0.y; fx[2]=xv0.z; fx[3]=xv0.w;
        fx[4]=xv1.x; fx[5]=xv1.y; fx[6]=xv1.z; fx[7]=xv1.w;
        fx[8]=xv2.x; fx[9]=xv2.y; fx[10]=xv2.z; fx[11]=xv2.w;
        fy[0]=yv0.x; fy[1]=yv0.y; fy[2]=yv0.z; fy[3]=yv0.w;
        fy[4]=yv1.x; fy[5]=yv1.y; fy[6]=yv1.z; fy[7]=yv1.w;
        fy[8]=yv2.x; fy[9]=yv2.y; fy[10]=yv2.z; fy[11]=yv2.w;

        float sx0=0.f,sx1=0.f,sx2=0.f, sy0=0.f,sy1=0.f,sy2=0.f, qq=0.f;
        float c00=0.f,c01=0.f,c02=0.f,c10=0.f,c11=0.f,c12=0.f,
              c20=0.f,c21=0.f,c22=0.f;

        #pragma unroll
        for (int p = 0; p < 4; ++p) {
            float px0=fx[3*p], px1=fx[3*p+1], px2=fx[3*p+2];
            float py0=fy[3*p], py1=fy[3*p+1], py2=fy[3*p+2];
            sx0+=px0; sx1+=px1; sx2+=px2;
            sy0+=py0; sy1+=py1; sy2+=py2;
            qq = fmaf(px0,px0,fmaf(px1,px1,fmaf(px2,px2,qq)));
            qq = fmaf(py0,py0,fmaf(py1,py1,fmaf(py2,py2,qq)));
            c00=fmaf(px0,py0,c00); c01=fmaf(px0,py1,c01); c02=fmaf(px0,py2,c02);
            c10=fmaf(px1,py0,c10); c11=fmaf(px1,py1,c11); c12=fmaf(px1,py2,c12);
            c20=fmaf(px2,py0,c20); c21=fmaf(px2,py1,c21); c22=fmaf(px2,py2,c22);
        }

        // DPP butterfly over the 16 channels. Stages: xor1, xor2 (quad_perm),
        // 8-group (half_mirror), 16-group (mirror), then row_bcast15 into rows
        // 1,3 only -> full 32-lane batch sums valid in lanes 16-31 / 48-63.
#define STAGE(C, M) \
        sx0=dpp_add<C,M>(sx0); sx1=dpp_add<C,M>(sx1); sx2=dpp_add<C,M>(sx2); \
        sy0=dpp_add<C,M>(sy0); sy1=dpp_add<C,M>(sy1); sy2=dpp_add<C,M>(sy2); \
        qq =dpp_add<C,M>(qq);                                                \
        c00=dpp_add<C,M>(c00); c01=dpp_add<C,M>(c01); c02=dpp_add<C,M>(c02); \
        c10=dpp_add<C,M>(c10); c11=dpp_add<C,M>(c11); c12=dpp_add<C,M>(c12); \
        c20=dpp_add<C,M>(c20); c21=dpp_add<C,M>(c21); c22=dpp_add<C,M>(c22);
        STAGE(0xB1, 0xF)    // quad_perm [1,0,3,2]  (xor 1)
        STAGE(0x4E, 0xF)    // quad_perm [2,3,0,1]  (xor 2)
        STAGE(0x141, 0xF)   // row_half_mirror      (8-group)
        STAGE(0x140, 0xF)   // row_mirror           (16-group)
        STAGE(0x142, 0xA)   // row_bcast15, rows 1&3 only (32-group)
#undef STAGE

        // Mean-centered covariance; Sx+Sy combined.
        float C00 = c00 - sx0*sy0*invN, C01 = c01 - sx0*sy1*invN, C02 = c02 - sx0*sy2*invN;
        float C10 = c10 - sx1*sy0*invN, C11 = c11 - sx1*sy1*invN, C12 = c12 - sx1*sy2*invN;
        float C20 = c20 - sx2*sy0*invN, C21 = c21 - sx2*sy1*invN, C22 = c22 - sx2*sy2*invN;
        float Sxy = qq - (sx0*sx0 + sx1*sx1 + sx2*sx2
                        + sy0*sy0 + sy1*sy1 + sy2*sy2) * invN;

        // A = C^T C; closed-form eigenvalues -> nuclear norm of C.
        float a00 = C00*C00 + C10*C10 + C20*C20;
        float a01 = C00*C01 + C10*C11 + C20*C21;
        float a02 = C00*C02 + C10*C12 + C20*C22;
        float a11 = C01*C01 + C11*C11 + C21*C21;
        float a12 = C01*C02 + C11*C12 + C21*C22;
        float a22 = C02*C02 + C12*C12 + C22*C22;

        float q = (a00 + a11 + a22) * (1.0f / 3.0f);
        float b00 = a00 - q, b11 = a11 - q, b22 = a22 - q;
        float p2 = (b00*b00 + b11*b11 + b22*b22
                    + 2.0f * (a01*a01 + a02*a02 + a12*a12)) * (1.0f / 6.0f);
        float p = __builtin_amdgcn_sqrtf(fmaxf(p2, 0.0f));
        float detB = b00 * (b11*b22 - a12*a12)
                   - a01 * (a01*b22 - a12*a02)
                   + a02 * (a01*a12 - b11*a02);
        float r = 0.5f * detB * __builtin_amdgcn_rcpf(p * p * p);
        r = fminf(1.0f, fmaxf(-1.0f, r));          // NaN (p==0) -> -1, harmless
        // phi in revolutions for v_cos: acos(r)/3 / (2*pi)
        float phi_rev = acos_fast(r) * 0.05305164769729845f;   // 1/(6*pi)
        float two_p = 2.0f * p;
        float l1 = q + two_p * __builtin_amdgcn_cosf(phi_rev);
        float l3 = q + two_p * __builtin_amdgcn_cosf(phi_rev + 0.33333333333f);
        float l2 = 3.0f * q - l1 - l3;
        float nuc = __builtin_amdgcn_sqrtf(fmaxf(l1, 0.0f))
                  + __builtin_amdgcn_sqrtf(fmaxf(l2, 0.0f))
                  + __builtin_amdgcn_sqrtf(fmaxf(l3, 0.0f));

        wave_acc += Sxy - 2.0f * nuc;   // valid in lanes 16-31 (batch 0), 48-63 (batch 1)
    }

    float t0 = __builtin_bit_cast(float, __builtin_amdgcn_readlane(
                   __builtin_bit_cast(int, wave_acc), 31));
    float t1 = __builtin_bit_cast(float, __builtin_amdgcn_readlane(
                   __builtin_bit_cast(int, wave_acc), 63));
    if (lane == 0) wsum[wave] = t0 + t1;
    __syncthreads();
    if (tid == 0) {
        float tsum = (wsum[0] + wsum[1] + wsum[2] + wsum[3]) * scale;
        atomicAdd(out, tsum);
    }
}

extern "C" void kernel_launch(void* const* d_in, const int* in_sizes, int n_in,
                              void* d_out, int out_size, void* d_ws, size_t ws_size,
                              hipStream_t stream) {
    const float4* x4 = (const float4*)d_in[0];
    const float4* y4 = (const float4*)d_in[1];
    float* out = (float*)d_out;

    const int B = in_sizes[0] / (NPTS * 3);             // 65536
    const int totalTiles = B / 2;                       // 32768
    const int tilesPerWave = totalTiles / TOTAL_WAVES;  // 4
    const float scale = 1.0f / ((float)B * (float)NPTS * 3.0f);

    hipMemsetAsync(out, 0, sizeof(float), stream);      // harness poisons d_out
    kabsch_kernel<<<BLOCKS, WPB * 64, 0, stream>>>(x4, y4, out, scale, tilesPerWave);
}

// Round 6
// 214.330 us; speedup vs baseline: 1.0110x; 1.0110x over previous
//
#include <hip/hip_runtime.h>
#include <math.h>

// KabschLoss: loss = mean( (xc @ R - yc)^2 ), R = U Vh from SVD of C = xc^T yc.
// Identity: sum |xc R - yc|^2 = Sx + Sy - 2*nuclear_norm(C). Only per-batch raw
// moments + singular values of the 3x3 covariance needed (verified exact R0-R4).
//
// R5: R2-R4 (global_load_lds DMA, 3 structures) all plateau at ~80 us /
// ~2.5 TB/s delivered; R1 proved the memory system does >=3.1 TB/s with plain
// vector loads. So: direct register dwordx4 streaming, lane stride 48 B
// (3 float4 = 4 whole points, phase 0) -> a wave's 3 loads cover a contiguous
// 3 KB span and fully consume every L2 line back-to-back (kills R1's 1.8x
// over-fetch). Register double-buffer across tiles (unroll 2), eigen+butterfly
// (~500 cy) as the load-use gap. launch_bounds(256,4): <=128 VGPR, 16 waves/CU,
// 1024 blocks = exactly 4 resident blocks/CU, no tail. No LDS in the loop.

#define NPTS 128
#define WPB 4
#define BLOCKS 1024
#define TOTAL_WAVES (BLOCKS * WPB)   // 4096
#define TILE_F4 192                  // float4 per array per 2-batch tile

template<int CTRL, int RMASK>
__device__ __forceinline__ float dpp_add(float v) {
    int t = __builtin_amdgcn_update_dpp(0, __builtin_bit_cast(int, v),
                                        CTRL, RMASK, 0xF, true);
    return v + __builtin_bit_cast(float, t);
}

__device__ __forceinline__ float acos_fast(float x) {
    // Abramowitz-Stegun 4.4.45: |err| <= 6.8e-5 rad on [0,1].
    float ax = fabsf(x);
    float p = fmaf(ax, -0.0187293f, 0.0742610f);
    p = fmaf(ax, p, -0.2121144f);
    p = fmaf(ax, p, 1.5707288f);
    float s = __builtin_amdgcn_sqrtf(fmaxf(1.0f - ax, 0.0f));
    float r = s * p;
    return (x < 0.0f) ? (3.14159265358979f - r) : r;
}

__global__ __launch_bounds__(256, 4) void kabsch_kernel(
        const float4* __restrict__ x4, const float4* __restrict__ y4,
        float* __restrict__ out, float scale, int tilesPerWave) {
    __shared__ float wsum[WPB];

    const int tid  = threadIdx.x;
    const int lane = tid & 63;
    const int wave = tid >> 6;
    const int w    = blockIdx.x * WPB + wave;
    const float invN = 1.0f / (float)NPTS;

    // Tile t for this wave: index w + t*TOTAL_WAVES. Lane reads float4s
    // [tile*192 + lane*3 + {0,1,2}] = floats [lane*12 .. lane*12+11] of the
    // tile = 4 whole points. Lanes 0-31 -> batch 2*tile, 32-63 -> 2*tile+1.
    const size_t base0 = (size_t)w * TILE_F4 + lane * 3;

    float4 ax0 = x4[base0], ax1 = x4[base0 + 1], ax2 = x4[base0 + 2];
    float4 ay0 = y4[base0], ay1 = y4[base0 + 1], ay2 = y4[base0 + 2];

    float wave_acc = 0.f;

    #pragma unroll 2
    for (int t = 0; t < tilesPerWave; ++t) {
        // Prefetch tile t+1 into the other register buffer (harmless reload of
        // tile 0 on the last iteration keeps this branchless).
        const size_t nb = (t + 1 < tilesPerWave)
            ? base0 + (size_t)(t + 1) * TOTAL_WAVES * TILE_F4 : base0;
        float4 bx0 = x4[nb], bx1 = x4[nb + 1], bx2 = x4[nb + 2];
        float4 by0 = y4[nb], by1 = y4[nb + 1], by2 = y4[nb + 2];

        // ---- Moments over this lane's 4 points (phase-0 layout).
        float sx0=0.f,sx1=0.f,sx2=0.f, sy0=0.f,sy1=0.f,sy2=0.f, qq=0.f;
        float c00=0.f,c01=0.f,c02=0.f,c10=0.f,c11=0.f,c12=0.f,
              c20=0.f,c21=0.f,c22=0.f;
#define ACC(px0,px1,px2,py0,py1,py2) do {                                  \
        sx0+=px0; sx1+=px1; sx2+=px2;                                      \
        sy0+=py0; sy1+=py1; sy2+=py2;                                      \
        qq = fmaf(px0,px0,fmaf(px1,px1,fmaf(px2,px2,qq)));                 \
        qq = fmaf(py0,py0,fmaf(py1,py1,fmaf(py2,py2,qq)));                 \
        c00=fmaf(px0,py0,c00); c01=fmaf(px0,py1,c01); c02=fmaf(px0,py2,c02); \
        c10=fmaf(px1,py0,c10); c11=fmaf(px1,py1,c11); c12=fmaf(px1,py2,c12); \
        c20=fmaf(px2,py0,c20); c21=fmaf(px2,py1,c21); c22=fmaf(px2,py2,c22); \
    } while (0)
        ACC(ax0.x, ax0.y, ax0.z,  ay0.x, ay0.y, ay0.z);
        ACC(ax0.w, ax1.x, ax1.y,  ay0.w, ay1.x, ay1.y);
        ACC(ax1.z, ax1.w, ax2.x,  ay1.z, ay1.w, ay2.x);
        ACC(ax2.y, ax2.z, ax2.w,  ay2.y, ay2.z, ay2.w);
#undef ACC

        // ---- DPP butterfly over the 16 channels (VALU pipe, verified R4).
        // xor1, xor2, 8-group, 16-group, then row_bcast15 into rows 1,3 only:
        // full 32-lane batch sums valid in lanes 16-31 / 48-63.
#define STAGE(C, M) \
        sx0=dpp_add<C,M>(sx0); sx1=dpp_add<C,M>(sx1); sx2=dpp_add<C,M>(sx2); \
        sy0=dpp_add<C,M>(sy0); sy1=dpp_add<C,M>(sy1); sy2=dpp_add<C,M>(sy2); \
        qq =dpp_add<C,M>(qq);                                                \
        c00=dpp_add<C,M>(c00); c01=dpp_add<C,M>(c01); c02=dpp_add<C,M>(c02); \
        c10=dpp_add<C,M>(c10); c11=dpp_add<C,M>(c11); c12=dpp_add<C,M>(c12); \
        c20=dpp_add<C,M>(c20); c21=dpp_add<C,M>(c21); c22=dpp_add<C,M>(c22);
        STAGE(0xB1, 0xF)    // quad_perm [1,0,3,2]  (xor 1)
        STAGE(0x4E, 0xF)    // quad_perm [2,3,0,1]  (xor 2)
        STAGE(0x141, 0xF)   // row_half_mirror      (8-group)
        STAGE(0x140, 0xF)   // row_mirror           (16-group)
        STAGE(0x142, 0xA)   // row_bcast15, rows 1&3 only (32-group)
#undef STAGE

        // ---- Mean-centered covariance; Sx+Sy combined.
        float C00 = c00 - sx0*sy0*invN, C01 = c01 - sx0*sy1*invN, C02 = c02 - sx0*sy2*invN;
        float C10 = c10 - sx1*sy0*invN, C11 = c11 - sx1*sy1*invN, C12 = c12 - sx1*sy2*invN;
        float C20 = c20 - sx2*sy0*invN, C21 = c21 - sx2*sy1*invN, C22 = c22 - sx2*sy2*invN;
        float Sxy = qq - (sx0*sx0 + sx1*sx1 + sx2*sx2
                        + sy0*sy0 + sy1*sy1 + sy2*sy2) * invN;

        // ---- A = C^T C; closed-form eigenvalues -> nuclear norm of C.
        float a00 = C00*C00 + C10*C10 + C20*C20;
        float a01 = C00*C01 + C10*C11 + C20*C21;
        float a02 = C00*C02 + C10*C12 + C20*C22;
        float a11 = C01*C01 + C11*C11 + C21*C21;
        float a12 = C01*C02 + C11*C12 + C21*C22;
        float a22 = C02*C02 + C12*C12 + C22*C22;

        float q = (a00 + a11 + a22) * (1.0f / 3.0f);
        float b00 = a00 - q, b11 = a11 - q, b22 = a22 - q;
        float p2 = (b00*b00 + b11*b11 + b22*b22
                    + 2.0f * (a01*a01 + a02*a02 + a12*a12)) * (1.0f / 6.0f);
        float p = __builtin_amdgcn_sqrtf(fmaxf(p2, 0.0f));
        float detB = b00 * (b11*b22 - a12*a12)
                   - a01 * (a01*b22 - a12*a02)
                   + a02 * (a01*a12 - b11*a02);
        float r = 0.5f * detB * __builtin_amdgcn_rcpf(p * p * p);
        r = fminf(1.0f, fmaxf(-1.0f, r));          // NaN (p==0) -> -1, harmless
        float phi_rev = acos_fast(r) * 0.05305164769729845f;   // acos/(6*pi): revolutions
        float two_p = 2.0f * p;
        float l1 = q + two_p * __builtin_amdgcn_cosf(phi_rev);
        float l3 = q + two_p * __builtin_amdgcn_cosf(phi_rev + 0.33333333333f);
        float l2 = 3.0f * q - l1 - l3;
        float nuc = __builtin_amdgcn_sqrtf(fmaxf(l1, 0.0f))
                  + __builtin_amdgcn_sqrtf(fmaxf(l2, 0.0f))
                  + __builtin_amdgcn_sqrtf(fmaxf(l3, 0.0f));

        wave_acc += Sxy - 2.0f * nuc;  // valid lanes 16-31 (batch 0), 48-63 (batch 1)

        // Rotate register double-buffer (copies vanish under unroll 2).
        ax0 = bx0; ax1 = bx1; ax2 = bx2;
        ay0 = by0; ay1 = by1; ay2 = by2;
    }

    float t0 = __builtin_bit_cast(float, __builtin_amdgcn_readlane(
                   __builtin_bit_cast(int, wave_acc), 31));
    float t1 = __builtin_bit_cast(float, __builtin_amdgcn_readlane(
                   __builtin_bit_cast(int, wave_acc), 63));
    if (lane == 0) wsum[wave] = t0 + t1;
    __syncthreads();
    if (tid == 0) {
        float tsum = (wsum[0] + wsum[1] + wsum[2] + wsum[3]) * scale;
        atomicAdd(out, tsum);
    }
}

extern "C" void kernel_launch(void* const* d_in, const int* in_sizes, int n_in,
                              void* d_out, int out_size, void* d_ws, size_t ws_size,
                              hipStream_t stream) {
    const float4* x4 = (const float4*)d_in[0];
    const float4* y4 = (const float4*)d_in[1];
    float* out = (float*)d_out;

    const int B = in_sizes[0] / (NPTS * 3);             // 65536
    const int totalTiles = B / 2;                       // 32768
    const int tilesPerWave = totalTiles / TOTAL_WAVES;  // 8
    const float scale = 1.0f / ((float)B * (float)NPTS * 3.0f);

    hipMemsetAsync(out, 0, sizeof(float), stream);      // harness poisons d_out
    kabsch_kernel<<<BLOCKS, WPB * 64, 0, stream>>>(x4, y4, out, scale, tilesPerWave);
}